// Round 1
// baseline (9154.312 us; speedup 1.0000x reference)
//
#include <hip/hip_runtime.h>
#include <math.h>

// Problem dims
#define Hh 1024
#define Dd 512
#define Aa 1024
#define Vv 50257
#define Ss 128
#define NSTEP 25

// Workspace offsets (in floats)
#define OFF_H      0        // 1024  current hidden state
#define OFF_GI     1024     // 3072  input gates (r,z,n)
#define OFF_GH     4096     // 3072  hidden gates (r,z,n)
#define OFF_MERGE  7168     // 2048  [h_new, attn]
#define OFF_Q      9216     // 1024  attention query
#define OFF_W      10240    // 128   attention weights
#define OFF_LOGITS 10368    // 50257 output logits
#define OFF_PM     60625    // 64    partial max
#define OFF_PL     60689    // 64    partial sumexp
#define OFF_PI     60753    // 64    partial argmax (int)
#define OFF_LSE    60817    // 1     log-sum-exp
#define OFF_WORD   60818    // 1     current token (int)

// ---------------- init: h = hidden[-1], word = SOS=1 ----------------
__global__ void k_init(const float* __restrict__ hidden, float* __restrict__ ws) {
    int i = blockIdx.x * blockDim.x + threadIdx.x;
    if (i < Hh) ws[OFF_H + i] = hidden[i];
    if (i == 0) ((int*)ws)[OFF_WORD] = 1;
}

// ---------------- GRU gate pre-activations: gi = W_ih@x + b_ih, gh = W_hh@h + b_hh
// one wave per output row (3072 rows), 4 waves/block -> 768 blocks
__global__ void k_gates(const float* __restrict__ E, const float* __restrict__ W_ih,
                        const float* __restrict__ W_hh, const float* __restrict__ b_ih,
                        const float* __restrict__ b_hh, float* __restrict__ ws) {
    int wave = (blockIdx.x * blockDim.x + threadIdx.x) >> 6;
    int lane = threadIdx.x & 63;
    if (wave >= 3 * Hh) return;
    int word = ((const int*)ws)[OFF_WORD];
    const float* x  = E + (size_t)word * Dd;
    const float* h  = ws + OFF_H;
    const float* wi = W_ih + (size_t)wave * Dd;
    const float* wh = W_hh + (size_t)wave * Hh;
    float accI = 0.f, accH = 0.f;
    for (int k = lane; k < Dd; k += 64) accI += wi[k] * x[k];
    for (int k = lane; k < Hh; k += 64) accH += wh[k] * h[k];
    for (int off = 32; off; off >>= 1) {
        accI += __shfl_down(accI, off);
        accH += __shfl_down(accH, off);
    }
    if (lane == 0) {
        ws[OFF_GI + wave] = accI + b_ih[wave];
        ws[OFF_GH + wave] = accH + b_hh[wave];
    }
}

// ---------------- GRU cell update: h_new, write merge[0:H] ----------------
__global__ void k_update(float* __restrict__ ws) {
    int i = blockIdx.x * blockDim.x + threadIdx.x;
    if (i >= Hh) return;
    float ir = ws[OFF_GI + i], iz = ws[OFF_GI + Hh + i], inn = ws[OFF_GI + 2 * Hh + i];
    float hr = ws[OFF_GH + i], hz = ws[OFF_GH + Hh + i], hn  = ws[OFF_GH + 2 * Hh + i];
    float r = 1.f / (1.f + expf(-(ir + hr)));
    float z = 1.f / (1.f + expf(-(iz + hz)));
    float n = tanhf(inn + r * hn);
    float h = ws[OFF_H + i];
    float hnew = (1.f - z) * n + z * h;
    ws[OFF_H + i] = hnew;
    ws[OFF_MERGE + i] = hnew;
}

// ---------------- query: q = Wq @ h_new (1024 rows, wave per row) ----------------
__global__ void k_query(const float* __restrict__ Wq, float* __restrict__ ws) {
    int wave = (blockIdx.x * blockDim.x + threadIdx.x) >> 6;
    int lane = threadIdx.x & 63;
    if (wave >= Aa) return;
    const float* h = ws + OFF_H;
    const float* w = Wq + (size_t)wave * Hh;
    float acc = 0.f;
    for (int k = lane; k < Hh; k += 64) acc += w[k] * h[k];
    for (int off = 32; off; off >>= 1) acc += __shfl_down(acc, off);
    if (lane == 0) ws[OFF_Q + wave] = acc;
}

// ---------------- scores + softmax (one block, 256 threads) ----------------
__global__ void k_scores(const float* __restrict__ emb, float* __restrict__ ws,
                         float* __restrict__ outw) {
    __shared__ float sc[Ss];
    __shared__ float red[4];
    int t = threadIdx.x, wave = t >> 6, lane = t & 63;
    const float* q = ws + OFF_Q;
    for (int s = wave; s < Ss; s += 4) {
        const float* e = emb + (size_t)s * Aa;
        float acc = 0.f;
        for (int k = lane; k < Aa; k += 64) acc += e[k] * q[k];
        for (int off = 32; off; off >>= 1) acc += __shfl_down(acc, off);
        if (lane == 0) sc[s] = acc;
    }
    __syncthreads();
    float v = (t < Ss) ? sc[t] : -1e30f;
    float m = v;
    for (int off = 32; off; off >>= 1) m = fmaxf(m, __shfl_down(m, off));
    if (lane == 0) red[wave] = m;
    __syncthreads();
    float mm = fmaxf(fmaxf(red[0], red[1]), fmaxf(red[2], red[3]));
    __syncthreads();
    float e = (t < Ss) ? expf(v - mm) : 0.f;
    float sum = e;
    for (int off = 32; off; off >>= 1) sum += __shfl_down(sum, off);
    if (lane == 0) red[wave] = sum;
    __syncthreads();
    float ss = red[0] + red[1] + red[2] + red[3];
    if (t < Ss) {
        float w = e / ss;
        ws[OFF_W + t] = w;
        outw[t] = w;
    }
}

// ---------------- attention combine: merge[H:H+A] = sum_s w[s]*emb[s,:] ----------------
__global__ void k_attn(const float* __restrict__ emb, float* __restrict__ ws) {
    int a = blockIdx.x * blockDim.x + threadIdx.x;
    if (a >= Aa) return;
    float acc = 0.f;
    for (int s = 0; s < Ss; s++) acc += ws[OFF_W + s] * emb[(size_t)s * Aa + a];
    ws[OFF_MERGE + Hh + a] = acc;
}

// ---------------- big matvec: logits = Wout @ merge + bout ----------------
// wave per row, 4 waves/block; merge staged in LDS; float4 loads of Wout row
__global__ void k_logits(const float* __restrict__ Wout, const float* __restrict__ bout,
                         float* __restrict__ ws) {
    __shared__ float sm[2048];
    for (int i = threadIdx.x; i < 2048; i += blockDim.x) sm[i] = ws[OFF_MERGE + i];
    __syncthreads();
    int wave_in = threadIdx.x >> 6, lane = threadIdx.x & 63;
    int row = blockIdx.x * 4 + wave_in;
    if (row >= Vv) return;
    const float4* wr = (const float4*)(Wout + (size_t)row * 2048);
    const float4* mr = (const float4*)sm;
    float acc = 0.f;
    for (int k = lane; k < 512; k += 64) {
        float4 w4 = wr[k];
        float4 m4 = mr[k];
        acc += w4.x * m4.x + w4.y * m4.y + w4.z * m4.z + w4.w * m4.w;
    }
    for (int off = 32; off; off >>= 1) acc += __shfl_down(acc, off);
    if (lane == 0) ws[OFF_LOGITS + row] = acc + bout[row];
}

// ---------------- stage-1 reduction: per-block online softmax + argmax ----------------
__global__ void k_reduce1(float* __restrict__ ws) {
    const float* logits = ws + OFF_LOGITS;
    __shared__ float smax[256], ssum[256];
    __shared__ int sidx[256];
    int t = threadIdx.x;
    int gid = blockIdx.x * 256 + t;
    float m = -1e30f, l = 0.f;
    int idx = 0;
    for (int i = gid; i < Vv; i += 64 * 256) {
        float v = logits[i];
        if (v > m) { l = l * expf(m - v) + 1.f; m = v; idx = i; }
        else       { l += expf(v - m); }
    }
    smax[t] = m; ssum[t] = l; sidx[t] = idx;
    __syncthreads();
    for (int stride = 128; stride; stride >>= 1) {
        if (t < stride) {
            float m1 = smax[t], l1 = ssum[t]; int i1 = sidx[t];
            float m2 = smax[t + stride], l2 = ssum[t + stride]; int i2 = sidx[t + stride];
            float M = fmaxf(m1, m2);
            float L = l1 * expf(m1 - M) + l2 * expf(m2 - M);
            int I = (m2 > m1) ? i2 : ((m2 < m1) ? i1 : min(i1, i2));
            smax[t] = M; ssum[t] = L; sidx[t] = I;
        }
        __syncthreads();
    }
    if (t == 0) {
        ws[OFF_PM + blockIdx.x] = smax[0];
        ws[OFF_PL + blockIdx.x] = ssum[0];
        ((int*)ws)[OFF_PI + blockIdx.x] = sidx[0];
    }
}

// ---------------- stage-2 reduction: final lse + token ----------------
__global__ void k_reduce2(float* __restrict__ ws, float* __restrict__ out_tok) {
    if (threadIdx.x != 0) return;
    float m = -1e30f, l = 0.f;
    int idx = 0;
    for (int b = 0; b < 64; b++) {
        float m2 = ws[OFF_PM + b], l2 = ws[OFF_PL + b];
        int i2 = ((const int*)ws)[OFF_PI + b];
        if (m2 > m)      { l = l * expf(m - m2) + l2; m = m2; idx = i2; }
        else if (m2 == m){ l += l2; idx = min(idx, i2); }
        else             { l += l2 * expf(m2 - m); }
    }
    float lse = m + logf(l);
    ws[OFF_LSE] = lse;
    ((int*)ws)[OFF_WORD] = idx;
    out_tok[0] = (float)idx;
}

// ---------------- write log-probs ----------------
__global__ void k_writelp(const float* __restrict__ ws, float* __restrict__ out_lp) {
    int i = blockIdx.x * blockDim.x + threadIdx.x;
    if (i >= Vv) return;
    out_lp[i] = ws[OFF_LOGITS + i] - ws[OFF_LSE];
}

extern "C" void kernel_launch(void* const* d_in, const int* in_sizes, int n_in,
                              void* d_out, int out_size, void* d_ws, size_t ws_size,
                              hipStream_t stream) {
    const float* hidden = (const float*)d_in[0];
    const float* emb    = (const float*)d_in[1];
    const float* E      = (const float*)d_in[2];
    const float* W_ih   = (const float*)d_in[3];
    const float* W_hh   = (const float*)d_in[4];
    const float* b_ih   = (const float*)d_in[5];
    const float* b_hh   = (const float*)d_in[6];
    const float* Wq     = (const float*)d_in[7];
    const float* Wout   = (const float*)d_in[8];
    const float* bout   = (const float*)d_in[9];

    float* ws = (float*)d_ws;
    float* out_lp  = (float*)d_out;                      // 25 x 50257
    float* out_w   = out_lp + (size_t)NSTEP * Vv;        // 25 x 128
    float* out_tok = out_w + (size_t)NSTEP * Ss;         // 25

    k_init<<<4, 256, 0, stream>>>(hidden, ws);
    for (int t = 0; t < NSTEP; t++) {
        k_gates  <<<768, 256, 0, stream>>>(E, W_ih, W_hh, b_ih, b_hh, ws);
        k_update <<<4, 256, 0, stream>>>(ws);
        k_query  <<<256, 256, 0, stream>>>(Wq, ws);
        k_scores <<<1, 256, 0, stream>>>(emb, ws, out_w + (size_t)t * Ss);
        k_attn   <<<4, 256, 0, stream>>>(emb, ws);
        k_logits <<<(Vv + 3) / 4, 256, 0, stream>>>(Wout, bout, ws);
        k_reduce1<<<64, 256, 0, stream>>>(ws);
        k_reduce2<<<1, 64, 0, stream>>>(ws, out_tok + t);
        k_writelp<<<(Vv + 255) / 256, 256, 0, stream>>>(ws, out_lp + (size_t)t * Vv);
    }
}

// Round 2
// 2515.416 us; speedup vs baseline: 3.6393x; 3.6393x over previous
//
#include <hip/hip_runtime.h>
#include <hip/hip_fp16.h>
#include <math.h>

// Problem dims
#define Hh 1024
#define Dd 512
#define Aa 1024
#define Vv 50257
#define Ss 128
#define NSTEP 25

// Workspace offsets (in floats)
#define OFF_H      0        // 1024  current hidden state
#define OFF_GI     1024     // 3072  input gates (r,z,n)
#define OFF_GH     4096     // 3072  hidden gates (r,z,n)
#define OFF_MERGE  7168     // 2048  [h_new, attn]
#define OFF_Q      9216     // 1024  attention query
#define OFF_LOGITS 10368    // 50257 output logits
#define OFF_PM     60625    // 64    partial max
#define OFF_PL     60689    // 64    partial sumexp
#define OFF_PI     60753    // 64    partial argmax (int)
#define OFF_WORD   60818    // 1     current token (int)

// fp16 Wout copy lives at byte offset 1 MB in ws (needs 206 MB; ws is ~1.6 GB)
#define WOUTH_BYTE_OFF (1u << 20)
#define NG_CONV (50257u * 256u)   // groups of 8 floats

// ---------------- Wout fp32 -> fp16 conversion (once per call) ----------------
__global__ void k_conv(const float4* __restrict__ src, uint4* __restrict__ dst, unsigned n8) {
    unsigned stride = gridDim.x * blockDim.x;
    for (unsigned g = blockIdx.x * blockDim.x + threadIdx.x; g < n8; g += stride) {
        float4 a = src[(size_t)g * 2], b = src[(size_t)g * 2 + 1];
        union { __half2 h[4]; uint4 u; } pk;
        pk.h[0] = __float22half2_rn(make_float2(a.x, a.y));
        pk.h[1] = __float22half2_rn(make_float2(a.z, a.w));
        pk.h[2] = __float22half2_rn(make_float2(b.x, b.y));
        pk.h[3] = __float22half2_rn(make_float2(b.z, b.w));
        dst[g] = pk.u;
    }
}

// ---------------- init: h = hidden[-1], word = SOS=1 ----------------
__global__ void k_init(const float* __restrict__ hidden, float* __restrict__ ws) {
    int i = blockIdx.x * blockDim.x + threadIdx.x;
    if (i < Hh) ws[OFF_H + i] = hidden[i];
    if (i == 0) ((int*)ws)[OFF_WORD] = 1;
}

// ---------------- GRU gate pre-activations (wave per row, float4) ----------------
__global__ void k_gates(const float* __restrict__ E, const float* __restrict__ W_ih,
                        const float* __restrict__ W_hh, const float* __restrict__ b_ih,
                        const float* __restrict__ b_hh, float* __restrict__ ws) {
    int gwave = (blockIdx.x * blockDim.x + threadIdx.x) >> 6;
    int lane = threadIdx.x & 63;
    if (gwave >= 3 * Hh) return;
    int word = ((const int*)ws)[OFF_WORD];
    const float4* x  = (const float4*)(E + (size_t)word * Dd);
    const float4* h  = (const float4*)(ws + OFF_H);
    const float4* wi = (const float4*)(W_ih + (size_t)gwave * Dd);
    const float4* wh = (const float4*)(W_hh + (size_t)gwave * Hh);
    float accI = 0.f, accH = 0.f;
    #pragma unroll
    for (int it = 0; it < 2; it++) {
        int k = it * 64 + lane;
        float4 a = wi[k], b = x[k];
        accI += a.x * b.x + a.y * b.y + a.z * b.z + a.w * b.w;
    }
    #pragma unroll
    for (int it = 0; it < 4; it++) {
        int k = it * 64 + lane;
        float4 a = wh[k], b = h[k];
        accH += a.x * b.x + a.y * b.y + a.z * b.z + a.w * b.w;
    }
    for (int off = 32; off; off >>= 1) {
        accI += __shfl_down(accI, off);
        accH += __shfl_down(accH, off);
    }
    if (lane == 0) {
        ws[OFF_GI + gwave] = accI + b_ih[gwave];
        ws[OFF_GH + gwave] = accH + b_hh[gwave];
    }
}

// ---------------- GRU cell update ----------------
__global__ void k_update(float* __restrict__ ws) {
    int i = blockIdx.x * blockDim.x + threadIdx.x;
    if (i >= Hh) return;
    float ir = ws[OFF_GI + i], iz = ws[OFF_GI + Hh + i], inn = ws[OFF_GI + 2 * Hh + i];
    float hr = ws[OFF_GH + i], hz = ws[OFF_GH + Hh + i], hn  = ws[OFF_GH + 2 * Hh + i];
    float r = 1.f / (1.f + expf(-(ir + hr)));
    float z = 1.f / (1.f + expf(-(iz + hz)));
    float n = tanhf(inn + r * hn);
    float h = ws[OFF_H + i];
    float hnew = (1.f - z) * n + z * h;
    ws[OFF_H + i] = hnew;
    ws[OFF_MERGE + i] = hnew;
}

// ---------------- query: q = Wq @ h_new (wave per row, float4) ----------------
__global__ void k_query(const float* __restrict__ Wq, float* __restrict__ ws) {
    int gwave = (blockIdx.x * blockDim.x + threadIdx.x) >> 6;
    int lane = threadIdx.x & 63;
    if (gwave >= Aa) return;
    const float4* h = (const float4*)(ws + OFF_H);
    const float4* w = (const float4*)(Wq + (size_t)gwave * Hh);
    float acc = 0.f;
    #pragma unroll
    for (int it = 0; it < 4; it++) {
        int k = it * 64 + lane;
        float4 a = w[k], b = h[k];
        acc += a.x * b.x + a.y * b.y + a.z * b.z + a.w * b.w;
    }
    for (int off = 32; off; off >>= 1) acc += __shfl_down(acc, off);
    if (lane == 0) ws[OFF_Q + gwave] = acc;
}

// ---------------- scores + softmax + attn combine (one block) ----------------
__global__ void k_scores_attn(const float* __restrict__ emb, float* __restrict__ ws,
                              float* __restrict__ outw) {
    __shared__ float sc[Ss];
    __shared__ float red[4];
    int t = threadIdx.x, wave = t >> 6, lane = t & 63;
    const float4* q = (const float4*)(ws + OFF_Q);
    for (int s = wave; s < Ss; s += 4) {
        const float4* e = (const float4*)(emb + (size_t)s * Aa);
        float acc = 0.f;
        #pragma unroll
        for (int it = 0; it < 4; it++) {
            int k = it * 64 + lane;
            float4 a = e[k], b = q[k];
            acc += a.x * b.x + a.y * b.y + a.z * b.z + a.w * b.w;
        }
        for (int off = 32; off; off >>= 1) acc += __shfl_down(acc, off);
        if (lane == 0) sc[s] = acc;
    }
    __syncthreads();
    float v = (t < Ss) ? sc[t] : -1e30f;
    float m = v;
    for (int off = 32; off; off >>= 1) m = fmaxf(m, __shfl_down(m, off));
    if (lane == 0) red[wave] = m;
    __syncthreads();
    float mm = fmaxf(fmaxf(red[0], red[1]), fmaxf(red[2], red[3]));
    __syncthreads();
    float e = (t < Ss) ? expf(v - mm) : 0.f;
    float sum = e;
    for (int off = 32; off; off >>= 1) sum += __shfl_down(sum, off);
    if (lane == 0) red[wave] = sum;
    __syncthreads();
    float ssum = red[0] + red[1] + red[2] + red[3];
    __syncthreads();
    if (t < Ss) {
        float w = e / ssum;
        sc[t] = w;
        outw[t] = w;
    }
    __syncthreads();
    // attn: merge[H + a] = sum_s w[s] * emb[s, a]  (coalesced across threads)
    for (int a = t; a < Aa; a += 256) {
        float acc = 0.f;
        for (int s = 0; s < Ss; s++) acc += sc[s] * emb[(size_t)s * Aa + a];
        ws[OFF_MERGE + Hh + a] = acc;
    }
}

// ---------------- big matvec: logits = WoutH(fp16) @ merge + bout ----------------
__global__ void k_logits(const uint4* __restrict__ WoutH, const float* __restrict__ bout,
                         float* __restrict__ ws) {
    __shared__ float4 sm[512];   // merge: 2048 floats
    const float4* mg = (const float4*)(ws + OFF_MERGE);
    for (int i = threadIdx.x; i < 512; i += blockDim.x) sm[i] = mg[i];
    __syncthreads();
    int wave = threadIdx.x >> 6, lane = threadIdx.x & 63;
    int row = blockIdx.x * 4 + wave;
    if (row >= Vv) return;
    const uint4* wr = WoutH + (size_t)row * 256;   // 2048 halves = 256 x uint4
    float acc = 0.f;
    #pragma unroll
    for (int it = 0; it < 4; it++) {
        int k = it * 64 + lane;
        union { uint4 u; __half2 h[4]; } pk;
        pk.u = wr[k];
        float4 m0 = sm[k * 2], m1 = sm[k * 2 + 1];
        float2 f0 = __half22float2(pk.h[0]);
        float2 f1 = __half22float2(pk.h[1]);
        float2 f2 = __half22float2(pk.h[2]);
        float2 f3 = __half22float2(pk.h[3]);
        acc += f0.x * m0.x + f0.y * m0.y + f1.x * m0.z + f1.y * m0.w
             + f2.x * m1.x + f2.y * m1.y + f3.x * m1.z + f3.y * m1.w;
    }
    for (int off = 32; off; off >>= 1) acc += __shfl_down(acc, off);
    if (lane == 0) ws[OFF_LOGITS + row] = acc + bout[row];
}

// ---------------- stage-1 reduction: per-block online softmax + argmax ----------------
__global__ void k_reduce1(float* __restrict__ ws) {
    const float* logits = ws + OFF_LOGITS;
    __shared__ float smax[256], ssum[256];
    __shared__ int sidx[256];
    int t = threadIdx.x;
    int gid = blockIdx.x * 256 + t;
    float m = -1e30f, l = 0.f;
    int idx = 0;
    for (int i = gid; i < Vv; i += 64 * 256) {
        float v = logits[i];
        if (v > m) { l = l * expf(m - v) + 1.f; m = v; idx = i; }
        else       { l += expf(v - m); }
    }
    smax[t] = m; ssum[t] = l; sidx[t] = idx;
    __syncthreads();
    for (int stride = 128; stride; stride >>= 1) {
        if (t < stride) {
            float m1 = smax[t], l1 = ssum[t]; int i1 = sidx[t];
            float m2 = smax[t + stride], l2 = ssum[t + stride]; int i2 = sidx[t + stride];
            float M = fmaxf(m1, m2);
            float L = l1 * expf(m1 - M) + l2 * expf(m2 - M);
            int I = (m2 > m1) ? i2 : ((m2 < m1) ? i1 : min(i1, i2));
            smax[t] = M; ssum[t] = L; sidx[t] = I;
        }
        __syncthreads();
    }
    if (t == 0) {
        ws[OFF_PM + blockIdx.x] = smax[0];
        ws[OFF_PL + blockIdx.x] = ssum[0];
        ((int*)ws)[OFF_PI + blockIdx.x] = sidx[0];
    }
}

// ---------------- final: merge 64 partials (per block), write lp; block 0 writes token
__global__ void k_final(float* __restrict__ ws, float* __restrict__ out_lp,
                        float* __restrict__ out_tok) {
    __shared__ float s_lse;
    int t = threadIdx.x;
    if (t < 64) {
        float m = ws[OFF_PM + t];
        float l = ws[OFF_PL + t];
        int idx = ((const int*)ws)[OFF_PI + t];
        for (int off = 32; off; off >>= 1) {
            float m2 = __shfl_down(m, off);
            float l2 = __shfl_down(l, off);
            int   i2 = __shfl_down(idx, off);
            float M = fmaxf(m, m2);
            float L = l * expf(m - M) + l2 * expf(m2 - M);
            int   I = (m2 > m) ? i2 : ((m2 < m) ? idx : min(idx, i2));
            m = M; l = L; idx = I;
        }
        if (t == 0) {
            s_lse = m + logf(l);
            if (blockIdx.x == 0) {
                ((int*)ws)[OFF_WORD] = idx;
                out_tok[0] = (float)idx;
            }
        }
    }
    __syncthreads();
    int i = blockIdx.x * 256 + t;
    if (i < Vv) out_lp[i] = ws[OFF_LOGITS + i] - s_lse;
}

extern "C" void kernel_launch(void* const* d_in, const int* in_sizes, int n_in,
                              void* d_out, int out_size, void* d_ws, size_t ws_size,
                              hipStream_t stream) {
    const float* hidden = (const float*)d_in[0];
    const float* emb    = (const float*)d_in[1];
    const float* E      = (const float*)d_in[2];
    const float* W_ih   = (const float*)d_in[3];
    const float* W_hh   = (const float*)d_in[4];
    const float* b_ih   = (const float*)d_in[5];
    const float* b_hh   = (const float*)d_in[6];
    const float* Wq     = (const float*)d_in[7];
    const float* Wout   = (const float*)d_in[8];
    const float* bout   = (const float*)d_in[9];

    float* ws = (float*)d_ws;
    uint4* WoutH = (uint4*)((char*)d_ws + WOUTH_BYTE_OFF);
    float* out_lp  = (float*)d_out;                      // 25 x 50257
    float* out_w   = out_lp + (size_t)NSTEP * Vv;        // 25 x 128
    float* out_tok = out_w + (size_t)NSTEP * Ss;         // 25

    k_conv<<<8192, 256, 0, stream>>>((const float4*)Wout, WoutH, NG_CONV);
    k_init<<<4, 256, 0, stream>>>(hidden, ws);
    for (int t = 0; t < NSTEP; t++) {
        k_gates      <<<768, 256, 0, stream>>>(E, W_ih, W_hh, b_ih, b_hh, ws);
        k_update     <<<4, 256, 0, stream>>>(ws);
        k_query      <<<256, 256, 0, stream>>>(Wq, ws);
        k_scores_attn<<<1, 256, 0, stream>>>(emb, ws, out_w + (size_t)t * Ss);
        k_logits     <<<(Vv + 3) / 4, 256, 0, stream>>>((const uint4*)WoutH, bout, ws);
        k_reduce1    <<<64, 256, 0, stream>>>(ws);
        k_final      <<<(Vv + 255) / 256, 256, 0, stream>>>(ws, out_lp + (size_t)t * Vv,
                                                            out_tok + t);
    }
}